// Round 10
// baseline (167.525 us; speedup 1.0000x reference)
//
#include <hip/hip_runtime.h>
#include <math.h>

typedef unsigned short u16;
typedef unsigned int   u32;
typedef unsigned long long u64;
typedef __attribute__((ext_vector_type(8))) short bf16x8;
typedef __attribute__((ext_vector_type(4))) float f32x4;
typedef __attribute__((ext_vector_type(4))) int i32x4;

#define TTOT  2052
#define NPERS 4
#define LSEQ  2048
#define WIN   128
#define NHEAD 16
#define HDIM  64
#define DM    1024
#define MPAD  2176   // 17 * 128
#define MSTEP 126    // output rows per gemm_qkv block (2-row conv halo)

__device__ __forceinline__ float bf2f(u16 u) {
    union { unsigned int i; float f; } v; v.i = ((unsigned int)u) << 16; return v.f;
}
__device__ __forceinline__ u16 f2bf(float f) {
    union { float f; unsigned int i; } v; v.f = f;
    unsigned int r = (v.i + 0x7fffu + ((v.i >> 16) & 1u)) >> 16;
    return (u16)r;
}
__device__ __forceinline__ u32 pk2(float lo, float hi) {
    return (u32)f2bf(lo) | ((u32)f2bf(hi) << 16);
}

// async global->LDS, 16B per lane; LDS dst = wave-uniform base + lane*16
__device__ __forceinline__ void glds16(const u16* g, u16* l) {
    __builtin_amdgcn_global_load_lds(
        (__attribute__((address_space(1))) void*)(g),
        (__attribute__((address_space(3))) void*)(l),
        16, 0, 0);
}

// ---------------- fp32 -> bf16 conversion / repack pass (exact 1D grid) ----------------
#define XP_UNITS (TTOT * DM / 4)
#define W_UNITS  (DM * DM / 4)
#define CVT_BLOCKS ((XP_UNITS + 4 * W_UNITS) / 256)

__global__ __launch_bounds__(256) void cvt(const float* __restrict__ x, const float* __restrict__ pm,
    const float* __restrict__ Wq, const float* __restrict__ Wk, const float* __restrict__ Wv,
    const float* __restrict__ Wo,
    u16* __restrict__ xp, u16* __restrict__ Wcat, u16* __restrict__ Woh,
    float* __restrict__ nsq)
{
    const int id = blockIdx.x * 256 + threadIdx.x;
    if (id < 2 * TTOT) nsq[id] = 0.f;           // zero norm accumulators (ws is poisoned)
    const float* s; u16* d;
    if (id < XP_UNITS) {
        const size_t e = (size_t)id * 4;
        const int row = (int)(e >> 10), c = (int)(e & 1023);
        s = (row < NPERS) ? (pm + (size_t)row * DM + c) : (x + (size_t)(row - NPERS) * DM + c);
        d = xp + e;
    } else {
        const int w   = id - XP_UNITS;
        const int sel = w >> 18;
        const size_t e = (size_t)(w & (W_UNITS - 1)) * 4;
        if (sel == 0)      { s = Wq + e; d = Wcat + e; }
        else if (sel == 1) { s = Wk + e; d = Wcat + (size_t)DM * DM + e; }
        else if (sel == 2) { s = Wv + e; d = Wcat + 2 * (size_t)DM * DM + e; }
        else               { s = Wo + e; d = Woh + e; }
    }
    f32x4 v = *(const f32x4*)s;
    *(u64*)d = (u64)pk2(v[0], v[1]) | ((u64)pk2(v[2], v[3]) << 32);
}

// ---------------- bf16 GEMM template (used by gemm_out): BK=64, XOR-swizzled LDS ----------------
template<int TM, int TN, bool OF32>
__device__ __forceinline__ void gemm_lds(const u16* __restrict__ Ablk, const u16* __restrict__ Bblk,
                                         void* __restrict__ Cbase, int mlim)
{
    __shared__ __align__(16) u16 As[TM * 64];
    __shared__ __align__(16) u16 Bs[TN * 64];
    const int tid  = threadIdx.x;
    const int lane = tid & 63;
    const int l15  = lane & 15, quad = lane >> 4;
    constexpr int RM = TM / 32, RN = TN / 32;
    const int wm = (tid >> 7) * (TM / 2);
    const int wn = ((tid >> 6) & 1) * (TN / 2);

    f32x4 acc[RM][RN];
    #pragma unroll
    for (int i = 0; i < RM; i++)
        #pragma unroll
        for (int j = 0; j < RN; j++) acc[i][j] = (f32x4){0.f, 0.f, 0.f, 0.f};

    constexpr int LA = TM / 32;
    constexpr int LB = TN / 32;

    for (int kk = 0; kk < DM; kk += 64) {
        #pragma unroll
        for (int i = 0; i < LA; i++) {
            const int e = i * 256 + tid;
            const int row = e >> 3, sc = (e & 7) ^ (row & 7);
            glds16(Ablk + (size_t)row * DM + kk + sc * 8, As + (size_t)e * 8);
        }
        #pragma unroll
        for (int i = 0; i < LB; i++) {
            const int e = i * 256 + tid;
            const int row = e >> 3, sc = (e & 7) ^ (row & 7);
            glds16(Bblk + (size_t)row * DM + kk + sc * 8, Bs + (size_t)e * 8);
        }
        __syncthreads();
        #pragma unroll
        for (int kc = 0; kc < 2; kc++) {
            bf16x8 af[RM], bfr[RN];
            #pragma unroll
            for (int i = 0; i < RM; i++)
                af[i]  = *(const bf16x8*)&As[(wm + i * 16 + l15) * 64 + (((kc * 4 + quad) ^ (l15 & 7)) * 8)];
            #pragma unroll
            for (int j = 0; j < RN; j++)
                bfr[j] = *(const bf16x8*)&Bs[(wn + j * 16 + l15) * 64 + (((kc * 4 + quad) ^ (l15 & 7)) * 8)];
            #pragma unroll
            for (int i = 0; i < RM; i++)
                #pragma unroll
                for (int j = 0; j < RN; j++)
                    acc[i][j] = __builtin_amdgcn_mfma_f32_16x16x32_bf16(af[i], bfr[j], acc[i][j], 0, 0, 0);
        }
        __syncthreads();
    }

    #pragma unroll
    for (int i = 0; i < RM; i++) {
        const int m0 = wm + i * 16 + quad * 4;
        #pragma unroll
        for (int j = 0; j < RN; j++) {
            const int n = wn + j * 16 + l15;
            #pragma unroll
            for (int r = 0; r < 4; r++) {
                const int m = m0 + r;
                if (m < mlim) {
                    if (OF32) ((float*)Cbase)[(size_t)m * DM + n] = acc[i][j][r];
                    else      ((u16*)Cbase)[(size_t)m * DM + n]   = f2bf(acc[i][j][r]);
                }
            }
        }
    }
}

__global__ __launch_bounds__(256) void gemm_out(const u16* __restrict__ AO, const u16* __restrict__ Woh,
                                                float* __restrict__ Cout)
{
    const int Mb = blockIdx.x * 64, Nb = blockIdx.y * 128;
    gemm_lds<64, 128, true>(AO + (size_t)Mb * DM, Woh + (size_t)Nb * DM,
                            (void*)(Cout + (size_t)Mb * DM + Nb), 64);
}

// ---------------- fused QKV GEMM + causal conv + SiLU (+ sumsq for Q/K norms) ----------------
// 128 staged raw rows = 2-row halo + 126 output rows. Raw tile round-trips through the
// (dead) staging LDS; each thread owns one channel, rolls 3 taps down its column.
// Reference zero-pads t<0, so taps are predicated on t>=1 / t>=2 (halo garbage never used).
// Q/K stay UNNORMALIZED; per-row sumsq accumulated into nsq[2][TTOT]; attn applies norms.
__global__ __launch_bounds__(256) void gemm_qkv_conv(
    const u16* __restrict__ xp, const u16* __restrict__ Wcat,
    const float* __restrict__ qw, const float* __restrict__ qb,
    const float* __restrict__ kw, const float* __restrict__ kb,
    const float* __restrict__ vw, const float* __restrict__ vb,
    u16* __restrict__ Qc, u16* __restrict__ Kc, u16* __restrict__ Vc,
    float* __restrict__ nsq)
{
    __shared__ __align__(16) u16 buf[128 * 129];   // union: As(8192) + Bs(8192) | Csc(128x129)
    u16* As = buf;
    u16* Bs = buf + 8192;

    const int tid  = threadIdx.x;
    const int lane = tid & 63;
    const int l15  = lane & 15, quad = lane >> 4;
    const int wm = (tid >> 7) * 64;
    const int wn = ((tid >> 6) & 1) * 64;

    const int bx = blockIdx.x;               // 0..16
    const int nb = blockIdx.y;               // 0..23
    const int Mh = bx * MSTEP - 2;           // first staged (halo) raw row
    const u16* Bblk = Wcat + (size_t)nb * 128 * DM;

    f32x4 acc[4][4];
    #pragma unroll
    for (int i = 0; i < 4; i++)
        #pragma unroll
        for (int j = 0; j < 4; j++) acc[i][j] = (f32x4){0.f, 0.f, 0.f, 0.f};

    for (int kk = 0; kk < DM; kk += 64) {
        #pragma unroll
        for (int i = 0; i < 4; i++) {
            const int e = i * 256 + tid;
            const int row = e >> 3, sc = (e & 7) ^ (row & 7);
            const int mg = max(Mh + row, 0);             // bx=0 halo clamps to row 0 (masked later)
            glds16(xp + (size_t)mg * DM + kk + sc * 8, As + (size_t)e * 8);
        }
        #pragma unroll
        for (int i = 0; i < 4; i++) {
            const int e = i * 256 + tid;
            const int row = e >> 3, sc = (e & 7) ^ (row & 7);
            glds16(Bblk + (size_t)row * DM + kk + sc * 8, Bs + (size_t)e * 8);
        }
        __syncthreads();
        #pragma unroll
        for (int kc = 0; kc < 2; kc++) {
            bf16x8 af[4], bfr[4];
            #pragma unroll
            for (int i = 0; i < 4; i++)
                af[i]  = *(const bf16x8*)&As[(wm + i * 16 + l15) * 64 + (((kc * 4 + quad) ^ (l15 & 7)) * 8)];
            #pragma unroll
            for (int j = 0; j < 4; j++)
                bfr[j] = *(const bf16x8*)&Bs[(wn + j * 16 + l15) * 64 + (((kc * 4 + quad) ^ (l15 & 7)) * 8)];
            #pragma unroll
            for (int i = 0; i < 4; i++)
                #pragma unroll
                for (int j = 0; j < 4; j++)
                    acc[i][j] = __builtin_amdgcn_mfma_f32_16x16x32_bf16(af[i], bfr[j], acc[i][j], 0, 0, 0);
        }
        __syncthreads();
    }

    // ---- raw tile (bf16) -> Csc, stride 129 ----
    #pragma unroll
    for (int i = 0; i < 4; i++)
        #pragma unroll
        for (int j = 0; j < 4; j++)
            #pragma unroll
            for (int r = 0; r < 4; r++)
                buf[(wm + i * 16 + quad * 4 + r) * 129 + (wn + j * 16 + l15)] = f2bf(acc[i][j][r]);
    __syncthreads();

    // ---- conv + SiLU down the column; one channel per thread ----
    const int part = nb >> 3;                 // 0:Q 1:K 2:V
    const int c    = tid & 127;
    const int ch   = (nb & 7) * 128 + c;
    const int half = tid >> 7;                // waves 0,1 -> even rows; 2,3 -> odd rows
    const float *w, *b; u16* dst;
    if (part == 0)      { w = qw; b = qb; dst = Qc; }
    else if (part == 1) { w = kw; b = kb; dst = Kc; }
    else                { w = vw; b = vb; dst = Vc; }
    const float w0 = w[ch * 3], w1 = w[ch * 3 + 1], w2 = w[ch * 3 + 2], bb = b[ch];
    float* nrow = nsq + part * TTOT;          // used only when part < 2

    for (int k = 0; k < 63; k++) {
        const int rloc = 2 + k * 2 + half;    // staged-row of output t (wave-uniform)
        const int t = Mh + rloc;
        if (t >= TTOT) break;
        const float x0  = bf2f(buf[rloc * 129 + c]);
        const float xm1 = (t >= 1) ? bf2f(buf[(rloc - 1) * 129 + c]) : 0.f;
        const float xm2 = (t >= 2) ? bf2f(buf[(rloc - 2) * 129 + c]) : 0.f;
        const float a = bb + w2 * x0 + w1 * xm1 + w0 * xm2;
        const float y = a / (1.f + __expf(-a));
        dst[(size_t)t * DM + ch] = f2bf(y);
        if (part < 2) {
            float ss = y * y;
            #pragma unroll
            for (int off = 32; off > 0; off >>= 1) ss += __shfl_down(ss, off, 64);
            if (lane == 0) atomicAdd(nrow + t, ss);
        }
    }
}

// ---------------- MFMA flash attention with deferred l2-norm ----------------
// Scores: s = (q.k_raw) * invq[row] * invk[key] * scale; |s| <= 0.125 by Cauchy-Schwarz,
// so the max-pass-free softmax stays exact. Ks/Ps union sized in u16 for the larger user.
#define QT     64
#define KTILES 13
#define KROWS  208
#define KPAD   224
#define VSTR   232     // Vt/Ps row stride (u16): 464B, 16B-aligned, 2-way banks

__global__ __launch_bounds__(256) void attn(const u16* __restrict__ Q, const u16* __restrict__ K,
                                            const u16* __restrict__ V, const float* __restrict__ nsq,
                                            u16* __restrict__ AO)
{
    const int h  = blockIdx.y;
    const int qb = blockIdx.x * QT;
    const int kstart = max(NPERS, qb + NPERS - (WIN - 1));
    const int nk = NPERS + (qb + NPERS + QT - 1) - kstart + 1;   // <= 195

    __shared__ __align__(16) u16 KP[64 * VSTR];    // 29,696 B union: Ks (13,312 u16) | Ps (14,848 u16)
    __shared__ __align__(16) u16 Vt[64 * VSTR];
    u16* Ks = KP;
    u16* Ps = KP;

    const int tid  = threadIdx.x;
    const int wv   = tid >> 6, lane = tid & 63, l15 = lane & 15, quad = lane >> 4;
    const int qloc0 = wv * 16;

    // ---- early independent loads: V (transposed, to regs), norm sums ----
    u32 vreg[28];
    #pragma unroll
    for (int i = 0; i < 28; i++) {
        const int i2 = wv * 2 + i * 8;
        const int g0 = (i2     < NPERS) ? i2     : min(kstart + i2     - NPERS, TTOT - 1);
        const int g1 = (i2 + 1 < NPERS) ? i2 + 1 : min(kstart + i2 + 1 - NPERS, TTOT - 1);
        vreg[i] = (u32)V[(size_t)g0 * DM + h * HDIM + lane]
                | ((u32)V[(size_t)g1 * DM + h * HDIM + lane] << 16);
    }
    float kss[KTILES];
    #pragma unroll
    for (int t = 0; t < KTILES; t++) {
        const int i = t * 16 + l15;
        const int gk = (i < NPERS) ? i : min(kstart + i - NPERS, TTOT - 1);
        kss[t] = nsq[TTOT + gk];
    }
    float qss[4];
    #pragma unroll
    for (int r = 0; r < 4; r++) qss[r] = nsq[qb + qloc0 + quad * 4 + r + NPERS];

    // ---- stage K rows via global_load_lds, XOR-swizzled chunks ----
    #pragma unroll
    for (int i = 0; i < 7; i++) {
        const int cdx = i * 256 + tid;
        if (cdx < KROWS * 8) {
            const int r  = cdx >> 3;
            const int sc = (cdx & 7) ^ (r & 7);
            const int g  = (r < NPERS) ? r : min(kstart + r - NPERS, TTOT - 1);
            glds16(K + (size_t)g * DM + h * HDIM + sc * 8, Ks + (size_t)cdx * 8);
        }
    }
    __syncthreads();

    const int tqrow = qb + qloc0 + l15 + NPERS;
    const bf16x8 qa0 = *(const bf16x8*)&Q[(size_t)tqrow * DM + h * HDIM + quad * 8];
    const bf16x8 qa1 = *(const bf16x8*)&Q[(size_t)tqrow * DM + h * HDIM + 32 + quad * 8];

    const int sw = l15 & 7;
    f32x4 st[KTILES];
    #pragma unroll
    for (int t = 0; t < KTILES; t++) {
        const bf16x8 kb0 = *(const bf16x8*)&Ks[(t * 16 + l15) * 64 + ((quad ^ sw) * 8)];
        const bf16x8 kb1 = *(const bf16x8*)&Ks[(t * 16 + l15) * 64 + (((4 + quad) ^ sw) * 8)];
        f32x4 z = (f32x4){0.f, 0.f, 0.f, 0.f};
        z = __builtin_amdgcn_mfma_f32_16x16x32_bf16(qa0, kb0, z, 0, 0, 0);
        z = __builtin_amdgcn_mfma_f32_16x16x32_bf16(qa1, kb1, z, 0, 0, 0);
        st[t] = z;
    }

    // ---- masked exp with deferred norms (no max-pass) + row sums ----
    const float scale = 0.125f;
    float iq[4];
    #pragma unroll
    for (int r = 0; r < 4; r++) iq[r] = scale / fmaxf(sqrtf(qss[r]), 1e-12f);
    float ssum[4] = {0.f, 0.f, 0.f, 0.f};
    #pragma unroll
    for (int t = 0; t < KTILES; t++) {
        const int i  = t * 16 + l15;
        const int kg = kstart + i - NPERS;
        const float ik = 1.f / fmaxf(sqrtf(kss[t]), 1e-12f);
        #pragma unroll
        for (int r = 0; r < 4; r++) {
            const int tqr = qb + qloc0 + quad * 4 + r + NPERS;
            const bool ok = (i < NPERS) || ((i < nk) && (kg >= tqr - (WIN - 1)) && (kg <= tqr));
            const float p = ok ? __expf(st[t][r] * ik * iq[r]) : 0.f;
            st[t][r] = p;
            ssum[r] += p;
        }
    }
    #pragma unroll
    for (int off = 1; off < 16; off <<= 1)
        #pragma unroll
        for (int r = 0; r < 4; r++) ssum[r] += __shfl_xor(ssum[r], off, 64);
    float inv[4];
    #pragma unroll
    for (int r = 0; r < 4; r++) inv[r] = 1.f / ssum[r];

    __syncthreads();   // all Ks reads done before Ps (aliased) writes

    // ---- commit V registers to LDS (transposed) ----
    #pragma unroll
    for (int i = 0; i < 28; i++) {
        const int i2 = wv * 2 + i * 8;
        *(u32*)&Vt[lane * VSTR + i2] = vreg[i];
    }
    // ---- write P (bf16); zero tail keys [208,224) ----
    #pragma unroll
    for (int t = 0; t < KTILES; t++)
        #pragma unroll
        for (int r = 0; r < 4; r++)
            Ps[(qloc0 + quad * 4 + r) * VSTR + t * 16 + l15] = f2bf(st[t][r] * inv[r]);
    *(u64*)&Ps[(qloc0 + l15) * VSTR + KROWS + quad * 4] = 0ULL;
    __syncthreads();

    // ---- PV ----
    f32x4 oacc[4];
    #pragma unroll
    for (int dt = 0; dt < 4; dt++) oacc[dt] = (f32x4){0.f, 0.f, 0.f, 0.f};
    for (int ks = 0; ks < KPAD / 32; ks++) {
        const bf16x8 pa = *(const bf16x8*)&Ps[(qloc0 + l15) * VSTR + ks * 32 + quad * 8];
        #pragma unroll
        for (int dt = 0; dt < 4; dt++) {
            const bf16x8 vb = *(const bf16x8*)&Vt[(dt * 16 + l15) * VSTR + ks * 32 + quad * 8];
            oacc[dt] = __builtin_amdgcn_mfma_f32_16x16x32_bf16(pa, vb, oacc[dt], 0, 0, 0);
        }
    }

    #pragma unroll
    for (int dt = 0; dt < 4; dt++)
        #pragma unroll
        for (int r = 0; r < 4; r++)
            AO[(size_t)(qb + qloc0 + quad * 4 + r) * DM + h * HDIM + dt * 16 + l15] = f2bf(oacc[dt][r]);
}

extern "C" void kernel_launch(void* const* d_in, const int* in_sizes, int n_in,
                              void* d_out, int out_size, void* d_ws, size_t ws_size,
                              hipStream_t stream)
{
    const float* x  = (const float*)d_in[0];
    const float* pm = (const float*)d_in[1];
    const float* Wq = (const float*)d_in[2];
    const float* Wk = (const float*)d_in[3];
    const float* Wv = (const float*)d_in[4];
    const float* Wo = (const float*)d_in[5];
    const float* qw = (const float*)d_in[6];
    const float* qb = (const float*)d_in[7];
    const float* kw = (const float*)d_in[8];
    const float* kb = (const float*)d_in[9];
    const float* vw = (const float*)d_in[10];
    const float* vb = (const float*)d_in[11];
    float* out = (float*)d_out;

    // workspace (u16 units), ~25 MB. AO aliases xp (dead after gemm_qkv_conv).
    u16* ws16 = (u16*)d_ws;
    const size_t SZ_W  = (size_t)DM * DM;
    const size_t SZ_R  = (size_t)TTOT * DM;
    const size_t SZ_XP = (size_t)MPAD * DM;
    u16* Woh  = ws16;
    u16* Qc   = Woh + SZ_W;
    u16* Kc   = Qc + SZ_R;
    u16* Vc   = Kc + SZ_R;
    u16* xp   = Vc + SZ_R;         u16* AO = xp;
    u16* Wcat = xp + SZ_XP;
    float* nsq = (float*)(Wcat + 3 * SZ_W);      // [2][TTOT] sumsq accumulators

    hipLaunchKernelGGL(cvt, dim3(CVT_BLOCKS), dim3(256), 0, stream,
                       x, pm, Wq, Wk, Wv, Wo, xp, Wcat, Woh, nsq);
    hipLaunchKernelGGL(gemm_qkv_conv, dim3(17, 24), dim3(256), 0, stream,
                       xp, Wcat, qw, qb, kw, kb, vw, vb, Qc, Kc, Vc, nsq);
    hipLaunchKernelGGL(attn, dim3(LSEQ / QT, NHEAD), dim3(256), 0, stream,
                       Qc, Kc, Vc, nsq, AO);
    hipLaunchKernelGGL(gemm_out, dim3(32, 8), dim3(256), 0, stream,
                       AO, Woh, out);
}

// Round 11
// 149.249 us; speedup vs baseline: 1.1225x; 1.1225x over previous
//
#include <hip/hip_runtime.h>
#include <math.h>

typedef unsigned short u16;
typedef unsigned int   u32;
typedef unsigned long long u64;
typedef __attribute__((ext_vector_type(8))) short bf16x8;
typedef __attribute__((ext_vector_type(4))) float f32x4;
typedef __attribute__((ext_vector_type(4))) int i32x4;

#define TTOT  2052
#define NPERS 4
#define LSEQ  2048
#define WIN   128
#define NHEAD 16
#define HDIM  64
#define DM    1024
#define MPAD  2176   // 17 * 128

__device__ __forceinline__ float bf2f(u16 u) {
    union { unsigned int i; float f; } v; v.i = ((unsigned int)u) << 16; return v.f;
}
__device__ __forceinline__ u16 f2bf(float f) {
    union { float f; unsigned int i; } v; v.f = f;
    unsigned int r = (v.i + 0x7fffu + ((v.i >> 16) & 1u)) >> 16;
    return (u16)r;
}
__device__ __forceinline__ u32 pk2(float lo, float hi) {
    return (u32)f2bf(lo) | ((u32)f2bf(hi) << 16);
}

// async global->LDS, 16B per lane; LDS dst = wave-uniform base + lane*16
__device__ __forceinline__ void glds16(const u16* g, u16* l) {
    __builtin_amdgcn_global_load_lds(
        (__attribute__((address_space(1))) void*)(g),
        (__attribute__((address_space(3))) void*)(l),
        16, 0, 0);
}

// ---------------- fp32 -> bf16 conversion / repack pass (exact 1D grid) ----------------
#define XP_UNITS (TTOT * DM / 4)
#define W_UNITS  (DM * DM / 4)
#define CVT_BLOCKS ((XP_UNITS + 4 * W_UNITS) / 256)

__global__ __launch_bounds__(256) void cvt(const float* __restrict__ x, const float* __restrict__ pm,
    const float* __restrict__ Wq, const float* __restrict__ Wk, const float* __restrict__ Wv,
    const float* __restrict__ Wo,
    u16* __restrict__ xp, u16* __restrict__ Wcat, u16* __restrict__ Woh)
{
    const int id = blockIdx.x * 256 + threadIdx.x;
    const float* s; u16* d;
    if (id < XP_UNITS) {
        const size_t e = (size_t)id * 4;
        const int row = (int)(e >> 10), c = (int)(e & 1023);
        s = (row < NPERS) ? (pm + (size_t)row * DM + c) : (x + (size_t)(row - NPERS) * DM + c);
        d = xp + e;
    } else {
        const int w   = id - XP_UNITS;
        const int sel = w >> 18;
        const size_t e = (size_t)(w & (W_UNITS - 1)) * 4;
        if (sel == 0)      { s = Wq + e; d = Wcat + e; }
        else if (sel == 1) { s = Wk + e; d = Wcat + (size_t)DM * DM + e; }
        else if (sel == 2) { s = Wv + e; d = Wcat + 2 * (size_t)DM * DM + e; }
        else               { s = Wo + e; d = Woh + e; }
    }
    f32x4 v = *(const f32x4*)s;
    *(u64*)d = (u64)pk2(v[0], v[1]) | ((u64)pk2(v[2], v[3]) << 32);
}

// ---------------- bf16 GEMM: C[tile] = A * B^T, BK=64, XOR-swizzled LDS ----------------
template<int TM, int TN, bool OF32>
__device__ __forceinline__ void gemm_lds(const u16* __restrict__ Ablk, const u16* __restrict__ Bblk,
                                         void* __restrict__ Cbase, int mlim)
{
    __shared__ __align__(16) u16 As[TM * 64];
    __shared__ __align__(16) u16 Bs[TN * 64];
    const int tid  = threadIdx.x;
    const int lane = tid & 63;
    const int l15  = lane & 15, quad = lane >> 4;
    constexpr int RM = TM / 32, RN = TN / 32;
    const int wm = (tid >> 7) * (TM / 2);
    const int wn = ((tid >> 6) & 1) * (TN / 2);

    f32x4 acc[RM][RN];
    #pragma unroll
    for (int i = 0; i < RM; i++)
        #pragma unroll
        for (int j = 0; j < RN; j++) acc[i][j] = (f32x4){0.f, 0.f, 0.f, 0.f};

    constexpr int LA = TM / 32;
    constexpr int LB = TN / 32;

    for (int kk = 0; kk < DM; kk += 64) {
        #pragma unroll
        for (int i = 0; i < LA; i++) {
            const int e = i * 256 + tid;
            const int row = e >> 3, sc = (e & 7) ^ (row & 7);
            glds16(Ablk + (size_t)row * DM + kk + sc * 8, As + (size_t)e * 8);
        }
        #pragma unroll
        for (int i = 0; i < LB; i++) {
            const int e = i * 256 + tid;
            const int row = e >> 3, sc = (e & 7) ^ (row & 7);
            glds16(Bblk + (size_t)row * DM + kk + sc * 8, Bs + (size_t)e * 8);
        }
        __syncthreads();
        #pragma unroll
        for (int kc = 0; kc < 2; kc++) {
            bf16x8 af[RM], bfr[RN];
            #pragma unroll
            for (int i = 0; i < RM; i++)
                af[i]  = *(const bf16x8*)&As[(wm + i * 16 + l15) * 64 + (((kc * 4 + quad) ^ (l15 & 7)) * 8)];
            #pragma unroll
            for (int j = 0; j < RN; j++)
                bfr[j] = *(const bf16x8*)&Bs[(wn + j * 16 + l15) * 64 + (((kc * 4 + quad) ^ (l15 & 7)) * 8)];
            #pragma unroll
            for (int i = 0; i < RM; i++)
                #pragma unroll
                for (int j = 0; j < RN; j++)
                    acc[i][j] = __builtin_amdgcn_mfma_f32_16x16x32_bf16(af[i], bfr[j], acc[i][j], 0, 0, 0);
        }
        __syncthreads();
    }

    #pragma unroll
    for (int i = 0; i < RM; i++) {
        const int m0 = wm + i * 16 + quad * 4;
        #pragma unroll
        for (int j = 0; j < RN; j++) {
            const int n = wn + j * 16 + l15;
            #pragma unroll
            for (int r = 0; r < 4; r++) {
                const int m = m0 + r;
                if (m < mlim) {
                    if (OF32) ((float*)Cbase)[(size_t)m * DM + n] = acc[i][j][r];
                    else      ((u16*)Cbase)[(size_t)m * DM + n]   = f2bf(acc[i][j][r]);
                }
            }
        }
    }
}

__global__ __launch_bounds__(256) void gemm_qkv(const u16* __restrict__ xp, const u16* __restrict__ Wcat,
    u16* __restrict__ Qr, u16* __restrict__ Kr, u16* __restrict__ Vr)
{
    const int Mb = blockIdx.x * 128;
    const int nb = blockIdx.y;
    u16* C = (nb < 8) ? Qr : (nb < 16) ? Kr : Vr;
    const int Ncol = (nb & 7) * 128;
    gemm_lds<128, 128, false>(xp + (size_t)Mb * DM,
                              Wcat + (size_t)nb * 128 * DM,
                              (void*)(C + (size_t)Mb * DM + Ncol),
                              TTOT - Mb);
}

__global__ __launch_bounds__(256) void gemm_out(const u16* __restrict__ AO, const u16* __restrict__ Woh,
                                                float* __restrict__ Cout)
{
    const int Mb = blockIdx.x * 64, Nb = blockIdx.y * 128;
    gemm_lds<64, 128, true>(AO + (size_t)Mb * DM, Woh + (size_t)Nb * DM,
                            (void*)(Cout + (size_t)Mb * DM + Nb), 64);
}

// ---------------- depthwise causal conv (K=3) + bias + SiLU + optional l2norm ----------------
__global__ __launch_bounds__(256) void conv_silu_norm(
    const u16* __restrict__ Qr, const u16* __restrict__ Kr, const u16* __restrict__ Vr,
    const float* __restrict__ qw, const float* __restrict__ qb,
    const float* __restrict__ kw, const float* __restrict__ kb,
    const float* __restrict__ vw, const float* __restrict__ vb,
    u16* __restrict__ Qc, u16* __restrict__ Kc, u16* __restrict__ Vc)
{
    const int t0 = blockIdx.x * 2;
    const int z  = blockIdx.y;
    const u16* raw; const float *w, *b; u16* out;
    if (z == 0)      { raw = Qr; w = qw; b = qb; out = Qc; }
    else if (z == 1) { raw = Kr; w = kw; b = kb; out = Kc; }
    else             { raw = Vr; w = vw; b = vb; out = Vc; }

    const int tid = threadIdx.x;
    const int d0  = tid * 4;

    const u16* r0 = raw + (size_t)t0 * DM + d0;
    const u64 cm2 = (t0 >= 2) ? *(const u64*)(r0 - 2 * DM) : 0ULL;
    const u64 cm1 = (t0 >= 1) ? *(const u64*)(r0 - DM)     : 0ULL;
    const u64 c0  = *(const u64*)r0;
    const u64 c1  = *(const u64*)(r0 + DM);
    const f32x4 bias = *(const f32x4*)(b + d0);
    const f32x4 w0v  = *(const f32x4*)(w + 3 * d0);
    const f32x4 w1v  = *(const f32x4*)(w + 3 * d0 + 4);
    const f32x4 w2v  = *(const f32x4*)(w + 3 * d0 + 8);
    const float warr[12] = {w0v[0], w0v[1], w0v[2], w0v[3],
                            w1v[0], w1v[1], w1v[2], w1v[3],
                            w2v[0], w2v[1], w2v[2], w2v[3]};

    float va[4], vb2[4];
    float ss0 = 0.f, ss1 = 0.f;
    #pragma unroll
    for (int c = 0; c < 4; c++) {
        const float xm2 = bf2f((u16)(cm2 >> (16 * c)));
        const float xm1 = bf2f((u16)(cm1 >> (16 * c)));
        const float x0  = bf2f((u16)(c0  >> (16 * c)));
        const float x1  = bf2f((u16)(c1  >> (16 * c)));
        const float w0 = warr[3*c], w1 = warr[3*c + 1], w2 = warr[3*c + 2];
        float a0 = bias[c] + w2 * x0 + w1 * xm1 + w0 * xm2;
        float a1 = bias[c] + w2 * x1 + w1 * x0  + w0 * xm1;
        const float y0 = a0 / (1.f + __expf(-a0));
        const float y1 = a1 / (1.f + __expf(-a1));
        va[c] = y0; vb2[c] = y1;
        ss0 += y0 * y0; ss1 += y1 * y1;
    }
    float inv0 = 1.f, inv1 = 1.f;
    if (z < 2) {
        #pragma unroll
        for (int off = 32; off > 0; off >>= 1) {
            ss0 += __shfl_down(ss0, off, 64);
            ss1 += __shfl_down(ss1, off, 64);
        }
        __shared__ float red[8];
        const int wv = tid >> 6, ln = tid & 63;
        if (ln == 0) { red[wv] = ss0; red[wv + 4] = ss1; }
        __syncthreads();
        inv0 = 1.f / fmaxf(sqrtf(red[0] + red[1] + red[2] + red[3]), 1e-12f);
        inv1 = 1.f / fmaxf(sqrtf(red[4] + red[5] + red[6] + red[7]), 1e-12f);
    }
    u64 o0 = 0, o1 = 0;
    #pragma unroll
    for (int c = 0; c < 4; c++) {
        o0 |= (u64)f2bf(va[c]  * inv0) << (16 * c);
        o1 |= (u64)f2bf(vb2[c] * inv1) << (16 * c);
    }
    *(u64*)(out + (size_t)t0 * DM + d0)      = o0;
    *(u64*)(out + (size_t)(t0 + 1) * DM + d0) = o1;
}

// ---------------- MFMA flash attention: 1 block = 1 head x 64 queries ----------------
// Ks (stride 64, XOR-chunk-swizzled, glds16-staged) and Ps (stride VSTR) share the
// KP union region sized in u16 for the LARGER user (Ps: 64*VSTR = 14,848 u16).
// V preloaded transposed into registers (latency hidden behind K-stage + QK),
// committed to LDS after QK. No softmax max-pass: ||q||,||k|| <= 1 so |s*scale| <= 0.125.
#define QT     64
#define KTILES 13
#define KROWS  208
#define KPAD   224
#define VSTR   232     // Vt/Ps row stride (u16): 464B, 16B-aligned, 2-way banks

__global__ __launch_bounds__(256) void attn(const u16* __restrict__ Q, const u16* __restrict__ K,
                                            const u16* __restrict__ V, u16* __restrict__ AO)
{
    const int h  = blockIdx.y;
    const int qb = blockIdx.x * QT;
    const int kstart = max(NPERS, qb + NPERS - (WIN - 1));
    const int nk = NPERS + (qb + NPERS + QT - 1) - kstart + 1;   // <= 195

    __shared__ __align__(16) u16 KP[64 * VSTR];    // 29,696 B union: Ks | Ps
    __shared__ __align__(16) u16 Vt[64 * VSTR];    // 29,696 B
    u16* Ks = KP;
    u16* Ps = KP;

    const int tid  = threadIdx.x;
    const int wv   = tid >> 6, lane = tid & 63, l15 = lane & 15, quad = lane >> 4;

    // ---- issue V transposed loads into registers FIRST (overlap with K staging + QK) ----
    u32 vreg[28];
    #pragma unroll
    for (int i = 0; i < 28; i++) {
        const int i2 = wv * 2 + i * 8;
        const int g0 = (i2     < NPERS) ? i2     : min(kstart + i2     - NPERS, TTOT - 1);
        const int g1 = (i2 + 1 < NPERS) ? i2 + 1 : min(kstart + i2 + 1 - NPERS, TTOT - 1);
        vreg[i] = (u32)V[(size_t)g0 * DM + h * HDIM + lane]
                | ((u32)V[(size_t)g1 * DM + h * HDIM + lane] << 16);
    }

    // ---- stage K rows via global_load_lds, XOR-swizzled chunks ----
    #pragma unroll
    for (int i = 0; i < 7; i++) {
        const int c = i * 256 + tid;
        if (c < KROWS * 8) {
            const int r  = c >> 3;
            const int sc = (c & 7) ^ (r & 7);
            const int g  = (r < NPERS) ? r : min(kstart + r - NPERS, TTOT - 1);
            glds16(K + (size_t)g * DM + h * HDIM + sc * 8, Ks + (size_t)c * 8);
        }
    }
    __syncthreads();

    const int qloc0 = wv * 16;
    const int tqrow = qb + qloc0 + l15 + NPERS;
    const bf16x8 qa0 = *(const bf16x8*)&Q[(size_t)tqrow * DM + h * HDIM + quad * 8];
    const bf16x8 qa1 = *(const bf16x8*)&Q[(size_t)tqrow * DM + h * HDIM + 32 + quad * 8];

    const int sw = l15 & 7;
    f32x4 st[KTILES];
    #pragma unroll
    for (int t = 0; t < KTILES; t++) {
        const bf16x8 kb0 = *(const bf16x8*)&Ks[(t * 16 + l15) * 64 + ((quad ^ sw) * 8)];
        const bf16x8 kb1 = *(const bf16x8*)&Ks[(t * 16 + l15) * 64 + (((4 + quad) ^ sw) * 8)];
        f32x4 z = (f32x4){0.f, 0.f, 0.f, 0.f};
        z = __builtin_amdgcn_mfma_f32_16x16x32_bf16(qa0, kb0, z, 0, 0, 0);
        z = __builtin_amdgcn_mfma_f32_16x16x32_bf16(qa1, kb1, z, 0, 0, 0);
        st[t] = z;
    }

    // ---- masked exp (no max-pass) + row sums ----
    const float scale = 0.125f;
    float ssum[4] = {0.f, 0.f, 0.f, 0.f};
    #pragma unroll
    for (int t = 0; t < KTILES; t++) {
        const int i  = t * 16 + l15;
        const int kg = kstart + i - NPERS;
        #pragma unroll
        for (int r = 0; r < 4; r++) {
            const int tqr = qb + qloc0 + quad * 4 + r + NPERS;
            const bool ok = (i < NPERS) || ((i < nk) && (kg >= tqr - (WIN - 1)) && (kg <= tqr));
            const float p = ok ? __expf(st[t][r] * scale) : 0.f;
            st[t][r] = p;
            ssum[r] += p;
        }
    }
    #pragma unroll
    for (int off = 1; off < 16; off <<= 1)
        #pragma unroll
        for (int r = 0; r < 4; r++) ssum[r] += __shfl_xor(ssum[r], off, 64);
    float inv[4];
    #pragma unroll
    for (int r = 0; r < 4; r++) inv[r] = 1.f / ssum[r];

    __syncthreads();   // all Ks reads done before Ps (aliased) writes

    // ---- commit V registers to LDS (transposed) ----
    #pragma unroll
    for (int i = 0; i < 28; i++) {
        const int i2 = wv * 2 + i * 8;
        *(u32*)&Vt[lane * VSTR + i2] = vreg[i];
    }
    // ---- write P (bf16); zero tail keys [208,224) ----
    #pragma unroll
    for (int t = 0; t < KTILES; t++)
        #pragma unroll
        for (int r = 0; r < 4; r++)
            Ps[(qloc0 + quad * 4 + r) * VSTR + t * 16 + l15] = f2bf(st[t][r] * inv[r]);
    *(u64*)&Ps[(qloc0 + l15) * VSTR + KROWS + quad * 4] = 0ULL;
    __syncthreads();

    // ---- PV ----
    f32x4 oacc[4];
    #pragma unroll
    for (int dt = 0; dt < 4; dt++) oacc[dt] = (f32x4){0.f, 0.f, 0.f, 0.f};
    for (int ks = 0; ks < KPAD / 32; ks++) {
        const bf16x8 pa = *(const bf16x8*)&Ps[(qloc0 + l15) * VSTR + ks * 32 + quad * 8];
        #pragma unroll
        for (int dt = 0; dt < 4; dt++) {
            const bf16x8 vb = *(const bf16x8*)&Vt[(dt * 16 + l15) * VSTR + ks * 32 + quad * 8];
            oacc[dt] = __builtin_amdgcn_mfma_f32_16x16x32_bf16(pa, vb, oacc[dt], 0, 0, 0);
        }
    }

    #pragma unroll
    for (int dt = 0; dt < 4; dt++)
        #pragma unroll
        for (int r = 0; r < 4; r++)
            AO[(size_t)(qb + qloc0 + quad * 4 + r) * DM + h * HDIM + dt * 16 + l15] = f2bf(oacc[dt][r]);
}

extern "C" void kernel_launch(void* const* d_in, const int* in_sizes, int n_in,
                              void* d_out, int out_size, void* d_ws, size_t ws_size,
                              hipStream_t stream)
{
    const float* x  = (const float*)d_in[0];
    const float* pm = (const float*)d_in[1];
    const float* Wq = (const float*)d_in[2];
    const float* Wk = (const float*)d_in[3];
    const float* Wv = (const float*)d_in[4];
    const float* Wo = (const float*)d_in[5];
    const float* qw = (const float*)d_in[6];
    const float* qb = (const float*)d_in[7];
    const float* kw = (const float*)d_in[8];
    const float* kb = (const float*)d_in[9];
    const float* vw = (const float*)d_in[10];
    const float* vb = (const float*)d_in[11];
    float* out = (float*)d_out;

    u16* ws16 = (u16*)d_ws;
    const size_t SZ_W  = (size_t)DM * DM;
    const size_t SZ_R  = (size_t)TTOT * DM;
    const size_t SZ_XP = (size_t)MPAD * DM;
    u16* Woh  = ws16;
    u16* Qr   = Woh + SZ_W;        u16* AO = Qr;
    u16* Kr   = Qr + SZ_R;
    u16* Vr   = Kr + SZ_R;
    u16* Vc   = Vr + SZ_R;
    u16* xp   = Vc + SZ_R;         u16* Qc = xp;
    u16* Wcat = xp + SZ_XP;        u16* Kc = Wcat;

    hipLaunchKernelGGL(cvt, dim3(CVT_BLOCKS), dim3(256), 0, stream,
                       x, pm, Wq, Wk, Wv, Wo, xp, Wcat, Woh);
    hipLaunchKernelGGL(gemm_qkv, dim3(17, 24), dim3(256), 0, stream,
                       xp, Wcat, Qr, Kr, Vr);
    hipLaunchKernelGGL(conv_silu_norm, dim3(TTOT / 2, 3), dim3(256), 0, stream,
                       Qr, Kr, Vr, qw, qb, kw, kb, vw, vb, Qc, Kc, Vc);
    hipLaunchKernelGGL(attn, dim3(LSEQ / QT, NHEAD), dim3(256), 0, stream,
                       Qc, Kc, Vc, AO);
    hipLaunchKernelGGL(gemm_out, dim3(32, 8), dim3(256), 0, stream,
                       AO, Woh, out);
}